// Round 1
// baseline (4904.085 us; speedup 1.0000x reference)
//
#include <hip/hip_runtime.h>
#include <math.h>

#define SQH 0.70710678118654752440f

// Problem constants
// B=32, TQ=1024, TK=512, C=256, N_MELS*R=320, KSZ=5, L=4
static constexpr int MQ = 32 * 1024;   // 32768 query rows
static constexpr int MK = 32 * 512;    // 16384 key rows

// ---------------- positional encoding ----------------
__global__ void pos_enc_kernel(float* __restrict__ pe, int T, float rate) {
    int idx = blockIdx.x * blockDim.x + threadIdx.x;
    if (idx >= T * 256) return;
    int t = idx >> 8;
    int k = idx & 255;
    float e = 2.0f * (float)(k >> 1) / 256.0f;
    float pw = powf(10000.0f, e);
    float ang = (float)t * ((float)t * rate / pw);
    pe[idx] = ((k & 1) == 0) ? sinf(ang) : cosf(ang);
}

// ---------------- shared micro-kernel ----------------
__device__ __forceinline__ void micro_fma(const float (&As)[16][64], const float (&Bs)[16][64],
                                          int ty, int tx, float (&acc)[4][4]) {
#pragma unroll
    for (int kk = 0; kk < 16; ++kk) {
        float4 a4 = *(const float4*)&As[kk][ty << 2];
        float4 b4 = *(const float4*)&Bs[kk][tx << 2];
        float aa[4] = {a4.x, a4.y, a4.z, a4.w};
        float bb[4] = {b4.x, b4.y, b4.z, b4.w};
#pragma unroll
        for (int i = 0; i < 4; ++i)
#pragma unroll
            for (int j = 0; j < 4; ++j)
                acc[i][j] = fmaf(aa[i], bb[j], acc[i][j]);
    }
}

// ---------------- generic NN GEMM ----------------
// C[M,N] = act(A[M,K] @ B[K,N] + bias [+ pe on A] [+ res, *SQH])
// batched via gridDim.z with strides sA,sB,sC (elements)
template<int ACT, bool HASPE, bool HASRES, bool HASBIAS>
__global__ __launch_bounds__(256)
void gemm_nn(const float* __restrict__ A, const float* __restrict__ Bw,
             const float* __restrict__ bias, const float* __restrict__ pe,
             const float* __restrict__ res, float* __restrict__ Cc,
             int M, int N, int K, int peT,
             long sA, long sB, long sC) {
    __shared__ float As[16][64];
    __shared__ float Bs[16][64];
    int z = blockIdx.z;
    A  += (long)z * sA;
    Bw += (long)z * sB;
    Cc += (long)z * sC;
    const float* resp = nullptr;
    if (HASRES) resp = res + (long)z * sC;
    int row0 = blockIdx.y * 64, col0 = blockIdx.x * 64;
    int tid = threadIdx.x;
    int ar = tid >> 2, ak = (tid & 3) << 2;       // A: 64 rows x 16 k, float4 per thread
    int bk = tid >> 4, bn = (tid & 15) << 2;      // B: 16 k   x 64 n, float4 per thread
    int tx = tid & 15, ty = tid >> 4;
    float acc[4][4] = {};
    for (int k0 = 0; k0 < K; k0 += 16) {
        // ---- stage A tile (K is always a multiple of 16 here) ----
        float4 av = make_float4(0.f, 0.f, 0.f, 0.f);
        int grow = row0 + ar;
        if (grow < M) {
            av = *(const float4*)(A + (long)grow * K + (k0 + ak));
            if (HASPE) {
                float4 pv = *(const float4*)(pe + (long)(grow % peT) * K + (k0 + ak));
                av.x += pv.x; av.y += pv.y; av.z += pv.z; av.w += pv.w;
            }
        }
        As[ak + 0][ar] = av.x; As[ak + 1][ar] = av.y;
        As[ak + 2][ar] = av.z; As[ak + 3][ar] = av.w;
        // ---- stage B tile ----
        {
            int gn = col0 + bn;
            int gk = k0 + bk;
            float4 bv;
            if (gn + 3 < N) {
                bv = *(const float4*)(Bw + (long)gk * N + gn);
            } else {
                bv.x = (gn + 0 < N) ? Bw[(long)gk * N + gn + 0] : 0.f;
                bv.y = (gn + 1 < N) ? Bw[(long)gk * N + gn + 1] : 0.f;
                bv.z = (gn + 2 < N) ? Bw[(long)gk * N + gn + 2] : 0.f;
                bv.w = (gn + 3 < N) ? Bw[(long)gk * N + gn + 3] : 0.f;
            }
            *(float4*)&Bs[bk][bn] = bv;
        }
        __syncthreads();
        micro_fma(As, Bs, ty, tx, acc);
        __syncthreads();
    }
    // ---- epilogue ----
#pragma unroll
    for (int i = 0; i < 4; ++i) {
        int r = row0 + (ty << 2) + i;
        if (r >= M) continue;
#pragma unroll
        for (int j = 0; j < 4; ++j) {
            int c = col0 + (tx << 2) + j;
            if (c >= N) continue;
            float v = acc[i][j];
            if (HASBIAS) v += bias[c];
            if (HASRES)  v = (v + resp[(long)r * N + c]) * SQH;
            if (ACT == 1) v = fmaxf(v, 0.f);
            if (ACT == 2) v = 1.f / (1.f + expf(-v));
            Cc[(long)r * N + c] = v;
        }
    }
}

// ---------------- batched NT GEMM: C = A @ B^T ----------------
// A [M,K], B [N,K] both row-major; M,N multiples of 64, K multiple of 16.
__global__ __launch_bounds__(256)
void gemm_nt(const float* __restrict__ A, const float* __restrict__ Bm,
             float* __restrict__ Cc, int M, int N, int K,
             long sA, long sB, long sC) {
    __shared__ float As[16][64];
    __shared__ float Bs[16][64];
    int z = blockIdx.z;
    A  += (long)z * sA;
    Bm += (long)z * sB;
    Cc += (long)z * sC;
    int row0 = blockIdx.y * 64, col0 = blockIdx.x * 64;
    int tid = threadIdx.x;
    int ar = tid >> 2, ak = (tid & 3) << 2;
    int tx = tid & 15, ty = tid >> 4;
    float acc[4][4] = {};
    for (int k0 = 0; k0 < K; k0 += 16) {
        float4 av = *(const float4*)(A  + (long)(row0 + ar) * K + (k0 + ak));
        As[ak + 0][ar] = av.x; As[ak + 1][ar] = av.y;
        As[ak + 2][ar] = av.z; As[ak + 3][ar] = av.w;
        float4 bv = *(const float4*)(Bm + (long)(col0 + ar) * K + (k0 + ak));
        Bs[ak + 0][ar] = bv.x; Bs[ak + 1][ar] = bv.y;
        Bs[ak + 2][ar] = bv.z; Bs[ak + 3][ar] = bv.w;
        __syncthreads();
        micro_fma(As, Bs, ty, tx, acc);
        __syncthreads();
    }
#pragma unroll
    for (int i = 0; i < 4; ++i) {
        long r = row0 + (ty << 2) + i;
#pragma unroll
        for (int j = 0; j < 4; ++j) {
            int c = col0 + (tx << 2) + j;
            Cc[r * N + c] = acc[i][j];
        }
    }
}

// ---------------- causal dilated conv as gathered GEMM ----------------
// Y[32768,512] = sum_{tap} shift(X, -(4-tap)*dil) @ W[tap]  + bias
// W viewed as [1280,512] row-major (= conv_w[l] flattened).
__global__ __launch_bounds__(256)
void conv_gemm(const float* __restrict__ X, const float* __restrict__ W,
               const float* __restrict__ bias, float* __restrict__ Y, int dil) {
    __shared__ float As[16][64];
    __shared__ float Bs[16][64];
    int row0 = blockIdx.y * 64, col0 = blockIdx.x * 64;
    int tid = threadIdx.x;
    int ar = tid >> 2, ak = (tid & 3) << 2;
    int bk = tid >> 4, bn = (tid & 15) << 2;
    int tx = tid & 15, ty = tid >> 4;
    float acc[4][4] = {};
    for (int k0 = 0; k0 < 1280; k0 += 16) {
        int tap = k0 >> 8;
        int ci  = (k0 & 255) + ak;
        int off = (4 - tap) * dil;
        int grow = row0 + ar;
        int t = grow & 1023;
        float4 av = make_float4(0.f, 0.f, 0.f, 0.f);
        if (t - off >= 0)
            av = *(const float4*)(X + (long)(grow - off) * 256 + ci);
        As[ak + 0][ar] = av.x; As[ak + 1][ar] = av.y;
        As[ak + 2][ar] = av.z; As[ak + 3][ar] = av.w;
        float4 bv = *(const float4*)(W + (long)(k0 + bk) * 512 + (col0 + bn));
        *(float4*)&Bs[bk][bn] = bv;
        __syncthreads();
        micro_fma(As, Bs, ty, tx, acc);
        __syncthreads();
    }
#pragma unroll
    for (int i = 0; i < 4; ++i) {
        long r = row0 + (ty << 2) + i;
#pragma unroll
        for (int j = 0; j < 4; ++j) {
            int c = col0 + (tx << 2) + j;
            Y[r * 512 + c] = acc[i][j] + bias[c];
        }
    }
}

// ---------------- GLU + residual (in-place on h) ----------------
__global__ __launch_bounds__(256)
void glu_kernel(float* __restrict__ h, const float* __restrict__ y) {
    long i = (long)blockIdx.x * 256 + threadIdx.x;   // over 32768*64 float4 groups
    long row = i >> 6;
    int c4 = (int)(i & 63) << 2;
    float4 a = *(const float4*)&y[row * 512 + c4];
    float4 g = *(const float4*)&y[row * 512 + 256 + c4];
    float4 hv = *(const float4*)&h[row * 256 + c4];
    float4 o;
    o.x = (hv.x + a.x / (1.f + expf(-g.x))) * SQH;
    o.y = (hv.y + a.y / (1.f + expf(-g.y))) * SQH;
    o.z = (hv.z + a.z / (1.f + expf(-g.z))) * SQH;
    o.w = (hv.w + a.w / (1.f + expf(-g.w))) * SQH;
    *(float4*)&h[row * 256 + c4] = o;
}

// ---------------- row softmax over 512, scaled by rsqrt(512) ----------------
__global__ __launch_bounds__(256)
void softmax_rows(float* __restrict__ aw) {
    int lane = threadIdx.x & 63;
    int wv = threadIdx.x >> 6;
    long row = (long)blockIdx.x * 4 + wv;
    float* p = aw + row * 512;
    float4 v0 = ((const float4*)p)[lane];
    float4 v1 = ((const float4*)p)[lane + 64];
    float m = fmaxf(fmaxf(fmaxf(v0.x, v0.y), fmaxf(v0.z, v0.w)),
                    fmaxf(fmaxf(v1.x, v1.y), fmaxf(v1.z, v1.w)));
#pragma unroll
    for (int s = 32; s; s >>= 1) m = fmaxf(m, __shfl_xor(m, s));
    v0.x = expf(v0.x - m); v0.y = expf(v0.y - m);
    v0.z = expf(v0.z - m); v0.w = expf(v0.w - m);
    v1.x = expf(v1.x - m); v1.y = expf(v1.y - m);
    v1.z = expf(v1.z - m); v1.w = expf(v1.w - m);
    float sum = v0.x + v0.y + v0.z + v0.w + v1.x + v1.y + v1.z + v1.w;
#pragma unroll
    for (int s = 32; s; s >>= 1) sum += __shfl_xor(sum, s);
    float sc = 0.04419417382415922f / sum;   // rsqrt(512) folded into al
    v0.x *= sc; v0.y *= sc; v0.z *= sc; v0.w *= sc;
    v1.x *= sc; v1.y *= sc; v1.z *= sc; v1.w *= sc;
    ((float4*)p)[lane] = v0;
    ((float4*)p)[lane + 64] = v1;
}

// ---------------- launch ----------------
extern "C" void kernel_launch(void* const* d_in, const int* in_sizes, int n_in,
                              void* d_out, int out_size, void* d_ws, size_t ws_size,
                              hipStream_t stream) {
    const float* inputs  = (const float*)d_in[0];
    const float* keys    = (const float*)d_in[1];
    const float* values  = (const float*)d_in[2];
    const float* w_first = (const float*)d_in[3];
    const float* b_first = (const float*)d_in[4];
    const float* fc_w    = (const float*)d_in[5];
    const float* fc_b    = (const float*)d_in[6];
    const float* conv_w  = (const float*)d_in[7];
    const float* conv_b  = (const float*)d_in[8];
    const float* w1 = (const float*)d_in[9];  const float* b1 = (const float*)d_in[10];
    const float* w2 = (const float*)d_in[11]; const float* b2 = (const float*)d_in[12];
    const float* w3 = (const float*)d_in[13]; const float* b3 = (const float*)d_in[14];
    const float* wo = (const float*)d_in[15]; const float* bo = (const float*)d_in[16];
    const float* w_done = (const float*)d_in[17]; const float* b_done = (const float*)d_in[18];
    const float* w_mel  = (const float*)d_in[19]; const float* b_mel  = (const float*)d_in[20];
    float* out = (float*)d_out;
    float* ws  = (float*)d_ws;

    // workspace layout (floats)
    float* peq = ws;                         // 1024*256      =   262144
    float* pek = peq + 262144;               //  512*256      =   131072
    float* hA  = pek + 131072;               // 32768*256     =  8388608  (also q_out / ctx)
    float* hB  = hA + 8388608;               // 32768*256     =  8388608  (h)
    float* y   = hB + 8388608;               // 32768*512     = 16777216  (also aw)
    float* ko  = y + 16777216;               // 16384*256     =  4194304
    float* vo  = ko + 4194304;               // 16384*256     =  4194304
    float* aw  = y;
    float* qo  = hA;
    float* ctx = hA;

    dim3 blk(256);

    pos_enc_kernel<<<1024, 256, 0, stream>>>(peq, 1024, 1.0f);
    pos_enc_kernel<<<512, 256, 0, stream>>>(pek, 512, 2.0f);

    // h = relu(inputs @ w_first + b_first)
    gemm_nn<1, false, false, true><<<dim3(4, 512, 1), blk, 0, stream>>>(
        inputs, w_first, b_first, nullptr, nullptr, hA, MQ, 256, 320, 0, 0, 0, 0);
    // 3 FC layers (ping-pong, ends in hB)
    gemm_nn<1, false, false, true><<<dim3(4, 512, 1), blk, 0, stream>>>(
        hA, fc_w + 0 * 65536, fc_b + 0 * 256, nullptr, nullptr, hB, MQ, 256, 256, 0, 0, 0, 0);
    gemm_nn<1, false, false, true><<<dim3(4, 512, 1), blk, 0, stream>>>(
        hB, fc_w + 1 * 65536, fc_b + 1 * 256, nullptr, nullptr, hA, MQ, 256, 256, 0, 0, 0, 0);
    gemm_nn<1, false, false, true><<<dim3(4, 512, 1), blk, 0, stream>>>(
        hA, fc_w + 2 * 65536, fc_b + 2 * 256, nullptr, nullptr, hB, MQ, 256, 256, 0, 0, 0, 0);
    float* h = hB;

    for (int l = 0; l < 4; ++l) {
        int dil = 1 << l;
        // conv block
        conv_gemm<<<dim3(8, 512, 1), blk, 0, stream>>>(
            h, conv_w + (long)l * 5 * 256 * 512, conv_b + l * 512, y, dil);
        glu_kernel<<<8192, 256, 0, stream>>>(h, y);
        // projections
        gemm_nn<0, true, false, true><<<dim3(4, 512, 1), blk, 0, stream>>>(
            h, w2 + (long)l * 65536, b2 + l * 256, peq, nullptr, qo, MQ, 256, 256, 1024, 0, 0, 0);
        gemm_nn<0, true, false, true><<<dim3(4, 256, 1), blk, 0, stream>>>(
            keys, w1 + (long)l * 65536, b1 + l * 256, pek, nullptr, ko, MK, 256, 256, 512, 0, 0, 0);
        gemm_nn<0, false, false, true><<<dim3(4, 256, 1), blk, 0, stream>>>(
            values, w3 + (long)l * 65536, b3 + l * 256, nullptr, nullptr, vo, MK, 256, 256, 0, 0, 0, 0);
        // aw = q @ k^T  (batched over 32)
        gemm_nt<<<dim3(8, 16, 32), blk, 0, stream>>>(
            qo, ko, aw, 1024, 512, 256, 1024 * 256, 512 * 256, 1024 * 512);
        // softmax (rsqrt(Tk) folded)
        softmax_rows<<<8192, 256, 0, stream>>>(aw);
        // ctx = al @ v   (batched)
        gemm_nn<0, false, false, false><<<dim3(4, 16, 32), blk, 0, stream>>>(
            aw, vo, nullptr, nullptr, nullptr, ctx, 1024, 256, 512, 0,
            1024 * 512, 512 * 256, 1024 * 256);
        // h = (ctx @ wo + bo + h) * SQH   (in-place residual)
        gemm_nn<0, false, true, true><<<dim3(4, 512, 1), blk, 0, stream>>>(
            ctx, wo + (long)l * 65536, bo + l * 256, nullptr, h, h, MQ, 256, 256, 0, 0, 0, 0);
    }

    // outputs
    gemm_nn<0, false, false, true><<<dim3(5, 512, 1), blk, 0, stream>>>(
        h, w_mel, b_mel, nullptr, nullptr, out, MQ, 320, 256, 0, 0, 0, 0);
    gemm_nn<2, false, false, true><<<dim3(1, 512, 1), blk, 0, stream>>>(
        h, w_done, b_done, nullptr, nullptr, out + 10485760, MQ, 2, 256, 0, 0, 0, 0);
    hipMemcpyAsync(out + 10551296, h, (size_t)8388608 * 4, hipMemcpyDeviceToDevice, stream);
}

// Round 2
// 1712.663 us; speedup vs baseline: 2.8634x; 2.8634x over previous
//
#include <hip/hip_runtime.h>
#include <hip/hip_bf16.h>
#include <math.h>

#define SQH 0.70710678118654752440f

typedef __bf16 bf16x8 __attribute__((ext_vector_type(8)));
typedef float f32x4 __attribute__((ext_vector_type(4)));

// ---------------- positional encoding ----------------
__global__ void pos_enc_kernel(float* __restrict__ pe, int T, float rate) {
    int idx = blockIdx.x * blockDim.x + threadIdx.x;
    if (idx >= T * 256) return;
    int t = idx >> 8;
    int k = idx & 255;
    float e = 2.0f * (float)(k >> 1) / 256.0f;
    float pw = powf(10000.0f, e);
    float ang = (float)t * ((float)t * rate / pw);
    pe[idx] = ((k & 1) == 0) ? sinf(ang) : cosf(ang);
}

// ---------------- weight transpose: src[R][C] f32 -> dst[C][R] (OUT type) ----------------
template<typename OUT>
__global__ __launch_bounds__(256) void transpose_k(const float* __restrict__ src,
                                                   OUT* __restrict__ dst,
                                                   int R, int Cc, long sS, long sD) {
    __shared__ float tile[32][33];
    src += (long)blockIdx.z * sS;
    dst += (long)blockIdx.z * sD;
    int c0 = blockIdx.x * 32, r0 = blockIdx.y * 32;
    int tx = threadIdx.x & 31, ty = threadIdx.x >> 5;
#pragma unroll
    for (int p = 0; p < 4; ++p)
        tile[ty + 8 * p][tx] = src[(long)(r0 + ty + 8 * p) * Cc + c0 + tx];
    __syncthreads();
#pragma unroll
    for (int p = 0; p < 4; ++p)
        dst[(long)(c0 + ty + 8 * p) * R + r0 + tx] = (OUT)tile[tx][ty + 8 * p];
}

// ---------------- universal MFMA GEMM ----------------
// C[M,N] = epi(A[M,K] (+pe) @ Bt[N,K]^T + bias)
// BT_BF16: Bt source dtype (1=bf16, 0=f32). PE: add pos-enc to A rows.
// BIAS_MODE: 0 none, 1 per-col, 2 per-row. EPI: 0 f32, 1 relu f32, 2 (v+res)*SQH f32, 3 bf16.
template<int BT_BF16, int PE, int BIAS_MODE, int EPI>
__global__ __launch_bounds__(256) void gemm_mfma(
    const float* __restrict__ A, const void* __restrict__ Btv,
    const float* __restrict__ bias, const float* __restrict__ pe,
    const float* __restrict__ res, void* __restrict__ Cout,
    int M, int N, int K, int peMask,
    long sA, long sB, long sC)
{
    __shared__ __align__(16) __bf16 As[128 * 32];
    __shared__ __align__(16) __bf16 Bs[128 * 32];
    const int z = blockIdx.z;
    A += (long)z * sA;
    const float*  Btf = (const float*)Btv + (long)z * sB;
    const __bf16* Bth = (const __bf16*)Btv + (long)z * sB;
    const int row0 = blockIdx.y * 128, col0 = blockIdx.x * 128;
    const int tid = threadIdx.x;
    const int srow = tid >> 1, sk0 = (tid & 1) << 4;
    const int wid = tid >> 6, lane = tid & 63;
    const int wm = (wid >> 1) << 6, wn = (wid & 1) << 6;
    const int lrow = lane & 15, lkp = lane >> 4;
    const int grow = row0 + srow;
    const int ncol = col0 + srow;

    f32x4 acc[4][4];
#pragma unroll
    for (int i = 0; i < 4; ++i)
#pragma unroll
        for (int j = 0; j < 4; ++j) acc[i][j] = (f32x4){0.f, 0.f, 0.f, 0.f};

    for (int k0 = 0; k0 < K; k0 += 32) {
        // ---- stage A (fp32 -> bf16, optional PE) ----
        {
            __align__(16) float fa[16];
            const float* ap = A + (long)grow * K + (k0 + sk0);
#pragma unroll
            for (int q = 0; q < 4; ++q) *(float4*)&fa[q * 4] = *(const float4*)(ap + q * 4);
            if (PE) {
                const float* pp = pe + (long)(grow & peMask) * K + (k0 + sk0);
#pragma unroll
                for (int q = 0; q < 16; ++q) fa[q] += pp[q];
            }
            __align__(16) __bf16 hb[16];
#pragma unroll
            for (int q = 0; q < 16; ++q) hb[q] = (__bf16)fa[q];
            *(bf16x8*)&As[srow * 32 + sk0]     = *(bf16x8*)&hb[0];
            *(bf16x8*)&As[srow * 32 + sk0 + 8] = *(bf16x8*)&hb[8];
        }
        // ---- stage B (Bt is [N][K]) ----
        {
            __align__(16) __bf16 hb[16];
            if (ncol < N) {
                if (BT_BF16) {
                    const __bf16* bp = Bth + (long)ncol * K + (k0 + sk0);
                    *(bf16x8*)&hb[0] = *(const bf16x8*)bp;
                    *(bf16x8*)&hb[8] = *(const bf16x8*)(bp + 8);
                } else {
                    __align__(16) float fb[16];
                    const float* bp = Btf + (long)ncol * K + (k0 + sk0);
#pragma unroll
                    for (int q = 0; q < 4; ++q) *(float4*)&fb[q * 4] = *(const float4*)(bp + q * 4);
#pragma unroll
                    for (int q = 0; q < 16; ++q) hb[q] = (__bf16)fb[q];
                }
            } else {
#pragma unroll
                for (int q = 0; q < 16; ++q) hb[q] = (__bf16)0.f;
            }
            *(bf16x8*)&Bs[srow * 32 + sk0]     = *(bf16x8*)&hb[0];
            *(bf16x8*)&Bs[srow * 32 + sk0 + 8] = *(bf16x8*)&hb[8];
        }
        __syncthreads();
        bf16x8 af[4], bfr[4];
        const __bf16* Ab = As + (wm + lrow) * 32 + lkp * 8;
        const __bf16* Bb = Bs + (wn + lrow) * 32 + lkp * 8;
#pragma unroll
        for (int i = 0; i < 4; ++i) af[i] = *(const bf16x8*)(Ab + i * 512);
#pragma unroll
        for (int j = 0; j < 4; ++j) bfr[j] = *(const bf16x8*)(Bb + j * 512);
#pragma unroll
        for (int i = 0; i < 4; ++i)
#pragma unroll
            for (int j = 0; j < 4; ++j)
                acc[i][j] = __builtin_amdgcn_mfma_f32_16x16x32_bf16(af[i], bfr[j], acc[i][j], 0, 0, 0);
        __syncthreads();
    }
    // ---- epilogue ----
    float*  Cf = (float*)Cout + (long)z * sC;
    __bf16* Cb = (__bf16*)Cout + (long)z * sC;
    const float* resp = res ? (res + (long)z * sC) : nullptr;
#pragma unroll
    for (int i = 0; i < 4; ++i) {
#pragma unroll
        for (int r = 0; r < 4; ++r) {
            const int gr = row0 + wm + i * 16 + lkp * 4 + r;
#pragma unroll
            for (int j = 0; j < 4; ++j) {
                const int gc = col0 + wn + j * 16 + lrow;
                if (gc >= N) continue;
                float v = acc[i][j][r];
                if (BIAS_MODE == 1) v += bias[gc];
                if (BIAS_MODE == 2) v += bias[gr];
                if (EPI == 1) v = fmaxf(v, 0.f);
                if (EPI == 2) v = (v + resp[(long)gr * N + gc]) * SQH;
                if (EPI == 3) Cb[(long)gr * N + gc] = (__bf16)v;
                else          Cf[(long)gr * N + gc] = v;
            }
        }
    }
}

// ---------------- causal dilated conv as gathered MFMA GEMM ----------------
// Y[32768,512] = gather(X) @ Wt[512,1280]^T + bias;  X fp32 [32768,256]
__global__ __launch_bounds__(256) void conv_mfma(
    const float* __restrict__ X, const __bf16* __restrict__ Wt,
    const float* __restrict__ bias, float* __restrict__ Y, int dil)
{
    __shared__ __align__(16) __bf16 As[128 * 32];
    __shared__ __align__(16) __bf16 Bs[128 * 32];
    const int row0 = blockIdx.y * 128, col0 = blockIdx.x * 128;
    const int tid = threadIdx.x;
    const int srow = tid >> 1, sk0 = (tid & 1) << 4;
    const int wid = tid >> 6, lane = tid & 63;
    const int wm = (wid >> 1) << 6, wn = (wid & 1) << 6;
    const int lrow = lane & 15, lkp = lane >> 4;
    const int grow = row0 + srow;
    const int ncol = col0 + srow;
    const int tIdx = grow & 1023;

    f32x4 acc[4][4];
#pragma unroll
    for (int i = 0; i < 4; ++i)
#pragma unroll
        for (int j = 0; j < 4; ++j) acc[i][j] = (f32x4){0.f, 0.f, 0.f, 0.f};

    for (int k0 = 0; k0 < 1280; k0 += 32) {
        const int kg = k0 + sk0;
        const int tap = kg >> 8;
        const int off = (4 - tap) * dil;
        {
            __align__(16) float fa[16] = {};
            if (tIdx >= off) {
                const float* ap = X + (long)(grow - off) * 256 + (kg & 255);
#pragma unroll
                for (int q = 0; q < 4; ++q) *(float4*)&fa[q * 4] = *(const float4*)(ap + q * 4);
            }
            __align__(16) __bf16 hb[16];
#pragma unroll
            for (int q = 0; q < 16; ++q) hb[q] = (__bf16)fa[q];
            *(bf16x8*)&As[srow * 32 + sk0]     = *(bf16x8*)&hb[0];
            *(bf16x8*)&As[srow * 32 + sk0 + 8] = *(bf16x8*)&hb[8];
        }
        {
            const __bf16* bp = Wt + (long)ncol * 1280 + kg;
            *(bf16x8*)&Bs[srow * 32 + sk0]     = *(const bf16x8*)bp;
            *(bf16x8*)&Bs[srow * 32 + sk0 + 8] = *(const bf16x8*)(bp + 8);
        }
        __syncthreads();
        bf16x8 af[4], bfr[4];
        const __bf16* Ab = As + (wm + lrow) * 32 + lkp * 8;
        const __bf16* Bb = Bs + (wn + lrow) * 32 + lkp * 8;
#pragma unroll
        for (int i = 0; i < 4; ++i) af[i] = *(const bf16x8*)(Ab + i * 512);
#pragma unroll
        for (int j = 0; j < 4; ++j) bfr[j] = *(const bf16x8*)(Bb + j * 512);
#pragma unroll
        for (int i = 0; i < 4; ++i)
#pragma unroll
            for (int j = 0; j < 4; ++j)
                acc[i][j] = __builtin_amdgcn_mfma_f32_16x16x32_bf16(af[i], bfr[j], acc[i][j], 0, 0, 0);
        __syncthreads();
    }
#pragma unroll
    for (int i = 0; i < 4; ++i) {
#pragma unroll
        for (int r = 0; r < 4; ++r) {
            const int gr = row0 + wm + i * 16 + lkp * 4 + r;
#pragma unroll
            for (int j = 0; j < 4; ++j) {
                const int gc = col0 + wn + j * 16 + lrow;
                Y[(long)gr * 512 + gc] = acc[i][j][r] + bias[gc];
            }
        }
    }
}

// ---------------- GLU + residual (in-place on h) ----------------
__global__ __launch_bounds__(256) void glu_kernel(float* __restrict__ h, const float* __restrict__ y) {
    long i = (long)blockIdx.x * 256 + threadIdx.x;
    long row = i >> 6;
    int c4 = (int)(i & 63) << 2;
    float4 a = *(const float4*)&y[row * 512 + c4];
    float4 g = *(const float4*)&y[row * 512 + 256 + c4];
    float4 hv = *(const float4*)&h[row * 256 + c4];
    float4 o;
    o.x = (hv.x + a.x / (1.f + expf(-g.x))) * SQH;
    o.y = (hv.y + a.y / (1.f + expf(-g.y))) * SQH;
    o.z = (hv.z + a.z / (1.f + expf(-g.z))) * SQH;
    o.w = (hv.w + a.w / (1.f + expf(-g.w))) * SQH;
    *(float4*)&h[row * 256 + c4] = o;
}

// ---------------- row softmax over 512, scaled by rsqrt(512) ----------------
__global__ __launch_bounds__(256) void softmax_rows(float* __restrict__ aw) {
    int lane = threadIdx.x & 63;
    int wv = threadIdx.x >> 6;
    long row = (long)blockIdx.x * 4 + wv;
    float* p = aw + row * 512;
    float4 v0 = ((const float4*)p)[lane];
    float4 v1 = ((const float4*)p)[lane + 64];
    float m = fmaxf(fmaxf(fmaxf(v0.x, v0.y), fmaxf(v0.z, v0.w)),
                    fmaxf(fmaxf(v1.x, v1.y), fmaxf(v1.z, v1.w)));
#pragma unroll
    for (int s = 32; s; s >>= 1) m = fmaxf(m, __shfl_xor(m, s));
    v0.x = expf(v0.x - m); v0.y = expf(v0.y - m);
    v0.z = expf(v0.z - m); v0.w = expf(v0.w - m);
    v1.x = expf(v1.x - m); v1.y = expf(v1.y - m);
    v1.z = expf(v1.z - m); v1.w = expf(v1.w - m);
    float sum = v0.x + v0.y + v0.z + v0.w + v1.x + v1.y + v1.z + v1.w;
#pragma unroll
    for (int s = 32; s; s >>= 1) sum += __shfl_xor(sum, s);
    float sc = 0.04419417382415922f / sum;
    v0.x *= sc; v0.y *= sc; v0.z *= sc; v0.w *= sc;
    v1.x *= sc; v1.y *= sc; v1.z *= sc; v1.w *= sc;
    ((float4*)p)[lane] = v0;
    ((float4*)p)[lane + 64] = v1;
}

// ---------------- done head: sigmoid(h @ w_done + b_done), N=2 ----------------
__global__ __launch_bounds__(256) void done_kernel(const float* __restrict__ h,
                                                   const float* __restrict__ w,
                                                   const float* __restrict__ b,
                                                   float* __restrict__ out) {
    int row = blockIdx.x * 4 + (threadIdx.x >> 6);
    int lane = threadIdx.x & 63;
    float4 hv = *(const float4*)(h + (long)row * 256 + lane * 4);
    float4 w0 = *(const float4*)(w + lane * 8);
    float4 w1 = *(const float4*)(w + lane * 8 + 4);
    float d0 = hv.x * w0.x + hv.y * w0.z + hv.z * w1.x + hv.w * w1.z;
    float d1 = hv.x * w0.y + hv.y * w0.w + hv.z * w1.y + hv.w * w1.w;
#pragma unroll
    for (int s = 32; s; s >>= 1) { d0 += __shfl_xor(d0, s); d1 += __shfl_xor(d1, s); }
    if (lane == 0) {
        out[(long)row * 2 + 0] = 1.f / (1.f + expf(-(d0 + b[0])));
        out[(long)row * 2 + 1] = 1.f / (1.f + expf(-(d1 + b[1])));
    }
}

// ---------------- launch ----------------
extern "C" void kernel_launch(void* const* d_in, const int* in_sizes, int n_in,
                              void* d_out, int out_size, void* d_ws, size_t ws_size,
                              hipStream_t stream) {
    const float* inputs  = (const float*)d_in[0];
    const float* keys    = (const float*)d_in[1];
    const float* values  = (const float*)d_in[2];
    const float* w_first = (const float*)d_in[3];
    const float* b_first = (const float*)d_in[4];
    const float* fc_w    = (const float*)d_in[5];
    const float* fc_b    = (const float*)d_in[6];
    const float* conv_w  = (const float*)d_in[7];
    const float* conv_b  = (const float*)d_in[8];
    const float* w1 = (const float*)d_in[9];  const float* b1 = (const float*)d_in[10];
    const float* w2 = (const float*)d_in[11]; const float* b2 = (const float*)d_in[12];
    const float* w3 = (const float*)d_in[13]; const float* b3 = (const float*)d_in[14];
    const float* wo = (const float*)d_in[15]; const float* bo = (const float*)d_in[16];
    const float* w_done = (const float*)d_in[17]; const float* b_done = (const float*)d_in[18];
    const float* w_mel  = (const float*)d_in[19]; const float* b_mel  = (const float*)d_in[20];
    float* out = (float*)d_out;
    float* ws  = (float*)d_ws;

    // workspace layout
    float* peq = ws;                           // 262144
    float* pek = peq + 262144;                 // 131072
    float* h   = pek + 131072;                 // 8388608
    float* qb  = h + 8388608;                  // 8388608 (fc ping / q_out / ctx)
    float* aw  = qb + 8388608;                 // 16777216 (conv y / attention weights)
    __bf16* kout  = (__bf16*)(aw + 16777216);  // 4194304 bf16
    __bf16* vT    = kout + 4194304;            // 4194304 bf16
    __bf16* wfT   = vT + 4194304;              // 81920
    __bf16* fcT   = wfT + 81920;               // 196608
    __bf16* convT = fcT + 196608;              // 2621440
    __bf16* w1T   = convT + 2621440;           // 262144
    __bf16* w2T   = w1T + 262144;              // 262144
    __bf16* woT   = w2T + 262144;              // 262144
    __bf16* wmT   = woT + 262144;              // 81920
    float*  w3T   = (float*)(wmT + 81920);     // 262144 f32
    float* y = aw;

    dim3 blk(256);

    pos_enc_kernel<<<1024, 256, 0, stream>>>(peq, 1024, 1.0f);
    pos_enc_kernel<<<512, 256, 0, stream>>>(pek, 512, 2.0f);

    // weight transposes (to [N][K])
    transpose_k<__bf16><<<dim3(8, 10, 1), blk, 0, stream>>>(w_first, wfT, 320, 256, 0, 0);
    transpose_k<__bf16><<<dim3(8, 8, 3), blk, 0, stream>>>(fc_w, fcT, 256, 256, 65536, 65536);
    transpose_k<__bf16><<<dim3(16, 40, 4), blk, 0, stream>>>(conv_w, convT, 1280, 512, 655360, 655360);
    transpose_k<__bf16><<<dim3(8, 8, 4), blk, 0, stream>>>(w1, w1T, 256, 256, 65536, 65536);
    transpose_k<__bf16><<<dim3(8, 8, 4), blk, 0, stream>>>(w2, w2T, 256, 256, 65536, 65536);
    transpose_k<__bf16><<<dim3(8, 8, 4), blk, 0, stream>>>(wo, woT, 256, 256, 65536, 65536);
    transpose_k<float ><<<dim3(8, 8, 4), blk, 0, stream>>>(w3, w3T, 256, 256, 65536, 65536);
    transpose_k<__bf16><<<dim3(10, 8, 1), blk, 0, stream>>>(w_mel, wmT, 256, 320, 0, 0);

    // h = relu(inputs @ w_first + b_first); FC chain ends in h
    gemm_mfma<1, 0, 1, 1><<<dim3(2, 256, 1), blk, 0, stream>>>(
        inputs, wfT, b_first, nullptr, nullptr, qb, 32768, 256, 320, 0, 0, 0, 0);
    gemm_mfma<1, 0, 1, 1><<<dim3(2, 256, 1), blk, 0, stream>>>(
        qb, fcT + 0 * 65536, fc_b + 0 * 256, nullptr, nullptr, h, 32768, 256, 256, 0, 0, 0, 0);
    gemm_mfma<1, 0, 1, 1><<<dim3(2, 256, 1), blk, 0, stream>>>(
        h, fcT + 1 * 65536, fc_b + 1 * 256, nullptr, nullptr, qb, 32768, 256, 256, 0, 0, 0, 0);
    gemm_mfma<1, 0, 1, 1><<<dim3(2, 256, 1), blk, 0, stream>>>(
        qb, fcT + 2 * 65536, fc_b + 2 * 256, nullptr, nullptr, h, 32768, 256, 256, 0, 0, 0, 0);

    for (int l = 0; l < 4; ++l) {
        int dil = 1 << l;
        conv_mfma<<<dim3(4, 256, 1), blk, 0, stream>>>(
            h, convT + (long)l * 655360, conv_b + l * 512, y, dil);
        glu_kernel<<<8192, 256, 0, stream>>>(h, y);
        // q = (h + peq) @ w2 + b2   (f32 out)
        gemm_mfma<1, 1, 1, 0><<<dim3(2, 256, 1), blk, 0, stream>>>(
            h, w2T + (long)l * 65536, b2 + l * 256, peq, nullptr, qb, 32768, 256, 256, 1023, 0, 0, 0);
        // k = (keys + pek) @ w1 + b1   (bf16 out, [N][K] layout for QK^T)
        gemm_mfma<1, 1, 1, 3><<<dim3(2, 128, 1), blk, 0, stream>>>(
            keys, w1T + (long)l * 65536, b1 + l * 256, pek, nullptr, kout, 16384, 256, 256, 511, 0, 0, 0);
        // vT_z = w3T @ values_z^T + b3(row)  (bf16 out [256][512] per batch)
        gemm_mfma<0, 0, 2, 3><<<dim3(4, 2, 32), blk, 0, stream>>>(
            w3T + (long)l * 65536, values, b3 + l * 256, nullptr, nullptr, vT,
            256, 512, 256, 0, 0, 512 * 256, 256 * 512);
        // aw_z = q_z @ k_z^T
        gemm_mfma<1, 0, 0, 0><<<dim3(4, 8, 32), blk, 0, stream>>>(
            qb, kout, nullptr, nullptr, nullptr, aw,
            1024, 512, 256, 0, 1024 * 256, 512 * 256, 1024 * 512);
        softmax_rows<<<8192, 256, 0, stream>>>(aw);
        // ctx_z = al_z @ v_z  (Bt = vT_z)
        gemm_mfma<1, 0, 0, 0><<<dim3(2, 8, 32), blk, 0, stream>>>(
            aw, vT, nullptr, nullptr, nullptr, qb,
            1024, 256, 512, 0, 1024 * 512, 256 * 512, 1024 * 256);
        // h = (ctx @ wo + bo + h) * SQH
        gemm_mfma<1, 0, 1, 2><<<dim3(2, 256, 1), blk, 0, stream>>>(
            qb, woT + (long)l * 65536, bo + l * 256, nullptr, h, h, 32768, 256, 256, 0, 0, 0, 0);
    }

    // outputs
    gemm_mfma<1, 0, 1, 0><<<dim3(3, 256, 1), blk, 0, stream>>>(
        h, wmT, b_mel, nullptr, nullptr, out, 32768, 320, 256, 0, 0, 0, 0);
    done_kernel<<<8192, 256, 0, stream>>>(h, w_done, b_done, out + 10485760);
    hipMemcpyAsync(out + 10551296, h, (size_t)8388608 * 4, hipMemcpyDeviceToDevice, stream);
}

// Round 4
// 1325.565 us; speedup vs baseline: 3.6996x; 1.2920x over previous
//
#include <hip/hip_runtime.h>
#include <hip/hip_bf16.h>
#include <math.h>

#define SQH 0.70710678118654752440f

typedef __bf16 bf16x8 __attribute__((ext_vector_type(8)));
typedef float f32x4 __attribute__((ext_vector_type(4)));

__device__ __forceinline__ void glds16(const void* g, void* l) {
    __builtin_amdgcn_global_load_lds((const __attribute__((address_space(1))) void*)g,
                                     (__attribute__((address_space(3))) void*)l, 16, 0, 0);
}

// ---------------- positional encoding table ----------------
__global__ void pos_enc_kernel(float* __restrict__ pe, int T, float rate) {
    int idx = blockIdx.x * blockDim.x + threadIdx.x;
    if (idx >= T * 256) return;
    int t = idx >> 8;
    int k = idx & 255;
    float e = 2.0f * (float)(k >> 1) / 256.0f;
    float pw = powf(10000.0f, e);
    float ang = (float)t * ((float)t * rate / pw);
    pe[idx] = ((k & 1) == 0) ? sinf(ang) : cosf(ang);
}

__global__ void zero_init(float* z) { z[threadIdx.x] = 0.f; }

// ---------------- f32 -> bf16 convert (groups of 8) ----------------
__global__ __launch_bounds__(256) void cvt_bf(const float* __restrict__ src,
                                              __bf16* __restrict__ dst, long n8) {
    long i = (long)blockIdx.x * 256 + threadIdx.x;
    if (i >= n8) return;
    const float* s = src + i * 8;
    float4 a = *(const float4*)s, b = *(const float4*)(s + 4);
    bf16x8 o;
    o[0] = (__bf16)a.x; o[1] = (__bf16)a.y; o[2] = (__bf16)a.z; o[3] = (__bf16)a.w;
    o[4] = (__bf16)b.x; o[5] = (__bf16)b.y; o[6] = (__bf16)b.z; o[7] = (__bf16)b.w;
    *(bf16x8*)(dst + i * 8) = o;
}

// ---------------- keys + pek -> bf16 ----------------
__global__ __launch_bounds__(256) void kpe_kernel(const float* __restrict__ keys,
                                                  const float* __restrict__ pek,
                                                  __bf16* __restrict__ dst) {
    long i = (long)blockIdx.x * 256 + threadIdx.x;   // 8-elem groups over [16384][256]
    long row = i >> 5; int c8 = (int)(i & 31) << 3;
    const float* kp = keys + row * 256 + c8;
    const float* pp = pek + (row & 511) * 256 + c8;
    float4 a = *(const float4*)kp, b = *(const float4*)(kp + 4);
    float4 p = *(const float4*)pp, q = *(const float4*)(pp + 4);
    bf16x8 o;
    o[0] = (__bf16)(a.x + p.x); o[1] = (__bf16)(a.y + p.y);
    o[2] = (__bf16)(a.z + p.z); o[3] = (__bf16)(a.w + p.w);
    o[4] = (__bf16)(b.x + q.x); o[5] = (__bf16)(b.y + q.y);
    o[6] = (__bf16)(b.z + q.z); o[7] = (__bf16)(b.w + q.w);
    *(bf16x8*)(dst + i * 8) = o;
}

// ---------------- weight transpose: src[R][C] f32 -> dst[C][R] bf16 ----------------
__global__ __launch_bounds__(256) void transpose_k(const float* __restrict__ src,
                                                   __bf16* __restrict__ dst,
                                                   int R, int Cc, long sS, long sD) {
    __shared__ float tile[32][33];
    src += (long)blockIdx.z * sS;
    dst += (long)blockIdx.z * sD;
    int c0 = blockIdx.x * 32, r0 = blockIdx.y * 32;
    int tx = threadIdx.x & 31, ty = threadIdx.x >> 5;
#pragma unroll
    for (int p = 0; p < 4; ++p)
        tile[ty + 8 * p][tx] = src[(long)(r0 + ty + 8 * p) * Cc + c0 + tx];
    __syncthreads();
#pragma unroll
    for (int p = 0; p < 4; ++p)
        dst[(long)(c0 + ty + 8 * p) * R + r0 + tx] = (__bf16)tile[tx][ty + 8 * p];
}

// ---------------- universal bf16 MFMA GEMM (global_load_lds staging) ----------------
// C = epi(A[M,K] @ Bt[N,K]^T + bias). BIAS_MODE: 0 none, 1 col, 2 row.
// ACT: 0 none, 1 relu. OUT_MODE: 0 f32, 1 bf16, 2 both. RES: 1 -> v=(v+res)*SQH.
template<int BIAS_MODE, int ACT, int OUT_MODE, int RES>
__global__ __launch_bounds__(256) void gemm_bf(
    const __bf16* __restrict__ A, const __bf16* __restrict__ Bt,
    const float* __restrict__ bias, const float* __restrict__ res,
    float* __restrict__ outF, __bf16* __restrict__ outB,
    int M, int N, int K, long sA, long sB, long sC)
{
    __shared__ __align__(16) __bf16 As[4096];
    __shared__ __align__(16) __bf16 Bs[4096];
    const int z = blockIdx.z;
    A += (long)z * sA;
    Bt += (long)z * sB;
    const int row0 = blockIdx.y << 7, col0 = blockIdx.x << 7;
    const int tid = threadIdx.x, wid = tid >> 6, lane = tid & 63;
    const int lrow = lane & 15, lkp = lane >> 4;
    const int wm = (wid >> 1) << 6, wn = (wid & 1) << 6;
    const int srow = (wid << 5) + (lane >> 2);   // rows [32w, 32w+16)
    const int kq8 = (lane & 3) << 3;
    const __bf16* Ap0 = A + (long)(row0 + srow) * K + kq8;
    const __bf16* Ap1 = Ap0 + (long)16 * K;
    int c0i = col0 + srow, c1i = col0 + srow + 16;
    if (c0i > N - 1) c0i = N - 1;
    if (c1i > N - 1) c1i = N - 1;
    const __bf16* Bp0 = Bt + (long)c0i * K + kq8;
    const __bf16* Bp1 = Bt + (long)c1i * K + kq8;
    __bf16* AsW = As + (wid << 10);
    __bf16* BsW = Bs + (wid << 10);

    f32x4 acc[4][4];
#pragma unroll
    for (int i = 0; i < 4; ++i)
#pragma unroll
        for (int j = 0; j < 4; ++j) acc[i][j] = (f32x4){0.f, 0.f, 0.f, 0.f};

    for (int k0 = 0; k0 < K; k0 += 32) {
        glds16(Ap0 + k0, AsW);
        glds16(Ap1 + k0, AsW + 512);
        glds16(Bp0 + k0, BsW);
        glds16(Bp1 + k0, BsW + 512);
        __syncthreads();
        bf16x8 af[4], bfr[4];
        const __bf16* Ar = As + (wm + lrow) * 32 + lkp * 8;
        const __bf16* Br = Bs + (wn + lrow) * 32 + lkp * 8;
#pragma unroll
        for (int i = 0; i < 4; ++i) af[i] = *(const bf16x8*)(Ar + i * 512);
#pragma unroll
        for (int j = 0; j < 4; ++j) bfr[j] = *(const bf16x8*)(Br + j * 512);
#pragma unroll
        for (int i = 0; i < 4; ++i)
#pragma unroll
            for (int j = 0; j < 4; ++j)
                acc[i][j] = __builtin_amdgcn_mfma_f32_16x16x32_bf16(af[i], bfr[j], acc[i][j], 0, 0, 0);
        __syncthreads();
    }

    float* oF = outF ? outF + (long)z * sC : nullptr;
    __bf16* oB = outB ? outB + (long)z * sC : nullptr;
    const float* resp = RES ? res + (long)z * sC : nullptr;
#pragma unroll
    for (int i = 0; i < 4; ++i) {
#pragma unroll
        for (int r = 0; r < 4; ++r) {
            const int gr = row0 + wm + i * 16 + lkp * 4 + r;
#pragma unroll
            for (int j = 0; j < 4; ++j) {
                const int gc = col0 + wn + j * 16 + lrow;
                if (gc >= N) continue;
                float v = acc[i][j][r];
                if (BIAS_MODE == 1) v += bias[gc];
                if (BIAS_MODE == 2) v += bias[gr];
                if (RES) v = (v + resp[(long)gr * N + gc]) * SQH;
                if (ACT == 1) v = fmaxf(v, 0.f);
                if (OUT_MODE == 0 || OUT_MODE == 2) oF[(long)gr * N + gc] = v;
                if (OUT_MODE == 1 || OUT_MODE == 2) oB[(long)gr * N + gc] = (__bf16)v;
            }
        }
    }
}

// ---------------- causal dilated conv as gathered MFMA GEMM ----------------
// y[32768,512](bf16) = gather(h_bf) @ Wt[512,1280]^T + bias
__global__ __launch_bounds__(256) void conv_bf(
    const __bf16* __restrict__ hbf, const __bf16* __restrict__ Wt,
    const float* __restrict__ bias, __bf16* __restrict__ y, int dil,
    const __bf16* __restrict__ zp)
{
    __shared__ __align__(16) __bf16 As[4096];
    __shared__ __align__(16) __bf16 Bs[4096];
    const int row0 = blockIdx.y << 7, col0 = blockIdx.x << 7;
    const int tid = threadIdx.x, wid = tid >> 6, lane = tid & 63;
    const int lrow = lane & 15, lkp = lane >> 4;
    const int wm = (wid >> 1) << 6, wn = (wid & 1) << 6;
    const int srow = (wid << 5) + (lane >> 2);
    const int kq8 = (lane & 3) << 3;
    const int grow = row0 + srow;
    const int t0 = (row0 & 1023) + srow;
    const __bf16* Bp0 = Wt + (long)(col0 + srow) * 1280 + kq8;
    const __bf16* Bp1 = Bp0 + (long)16 * 1280;
    __bf16* AsW = As + (wid << 10);
    __bf16* BsW = Bs + (wid << 10);

    f32x4 acc[4][4];
#pragma unroll
    for (int i = 0; i < 4; ++i)
#pragma unroll
        for (int j = 0; j < 4; ++j) acc[i][j] = (f32x4){0.f, 0.f, 0.f, 0.f};

    for (int k0 = 0; k0 < 1280; k0 += 32) {
        const int tap = k0 >> 8;
        const int off = (4 - tap) * dil;
        const int kc = (k0 & 255) + kq8;
        const __bf16* a0 = (t0 >= off) ? hbf + (long)(grow - off) * 256 + kc : zp;
        const __bf16* a1 = (t0 + 16 >= off) ? hbf + (long)(grow + 16 - off) * 256 + kc : zp;
        glds16(a0, AsW);
        glds16(a1, AsW + 512);
        glds16(Bp0 + k0, BsW);
        glds16(Bp1 + k0, BsW + 512);
        __syncthreads();
        bf16x8 af[4], bfr[4];
        const __bf16* Ar = As + (wm + lrow) * 32 + lkp * 8;
        const __bf16* Br = Bs + (wn + lrow) * 32 + lkp * 8;
#pragma unroll
        for (int i = 0; i < 4; ++i) af[i] = *(const bf16x8*)(Ar + i * 512);
#pragma unroll
        for (int j = 0; j < 4; ++j) bfr[j] = *(const bf16x8*)(Br + j * 512);
#pragma unroll
        for (int i = 0; i < 4; ++i)
#pragma unroll
            for (int j = 0; j < 4; ++j)
                acc[i][j] = __builtin_amdgcn_mfma_f32_16x16x32_bf16(af[i], bfr[j], acc[i][j], 0, 0, 0);
        __syncthreads();
    }
#pragma unroll
    for (int i = 0; i < 4; ++i) {
#pragma unroll
        for (int r = 0; r < 4; ++r) {
            const int gr = row0 + wm + i * 16 + lkp * 4 + r;
#pragma unroll
            for (int j = 0; j < 4; ++j) {
                const int gc = col0 + wn + j * 16 + lrow;
                y[(long)gr * 512 + gc] = (__bf16)(acc[i][j][r] + bias[gc]);
            }
        }
    }
}

// ---------------- GLU + residual; writes h(f32), h_bf, hq_bf=bf16(h+peq) ----------------
__global__ __launch_bounds__(256) void glu_kernel(float* __restrict__ h,
                                                  const __bf16* __restrict__ y,
                                                  const float* __restrict__ peq,
                                                  __bf16* __restrict__ h_bf,
                                                  __bf16* __restrict__ hq_bf) {
    long i = (long)blockIdx.x * 256 + threadIdx.x;   // 8-elem groups over [32768][256]
    long row = i >> 5; int c8 = (int)(i & 31) << 3;
    bf16x8 av = *(const bf16x8*)&y[row * 512 + c8];
    bf16x8 gv = *(const bf16x8*)&y[row * 512 + 256 + c8];
    float* hp = &h[row * 256 + c8];
    float4 h0 = *(float4*)hp, h1 = *(float4*)(hp + 4);
    const float* pp = &peq[(row & 1023) * 256 + c8];
    float4 p0 = *(const float4*)pp, p1 = *(const float4*)(pp + 4);
    float hv[8] = {h0.x, h0.y, h0.z, h0.w, h1.x, h1.y, h1.z, h1.w};
    float pv[8] = {p0.x, p0.y, p0.z, p0.w, p1.x, p1.y, p1.z, p1.w};
    float o[8];
    bf16x8 ob, oq;
#pragma unroll
    for (int q = 0; q < 8; ++q) {
        float a = (float)av[q], g = (float)gv[q];
        float v = (hv[q] + a / (1.f + expf(-g))) * SQH;
        o[q] = v;
        ob[q] = (__bf16)v;
        oq[q] = (__bf16)(v + pv[q]);
    }
    *(float4*)hp = make_float4(o[0], o[1], o[2], o[3]);
    *(float4*)(hp + 4) = make_float4(o[4], o[5], o[6], o[7]);
    *(bf16x8*)&h_bf[row * 256 + c8] = ob;
    *(bf16x8*)&hq_bf[row * 256 + c8] = oq;
}

// ---------------- in-place bf16 row softmax over 512 (rsqrt(512) folded) ----------------
__global__ __launch_bounds__(256) void softmax_bf(__bf16* __restrict__ aw) {
    int wv = threadIdx.x >> 6, lane = threadIdx.x & 63;
    long row = (long)blockIdx.x * 4 + wv;
    __bf16* p = aw + row * 512 + lane * 8;
    bf16x8 v = *(const bf16x8*)p;
    float f[8];
#pragma unroll
    for (int q = 0; q < 8; ++q) f[q] = (float)v[q];
    float m = f[0];
#pragma unroll
    for (int q = 1; q < 8; ++q) m = fmaxf(m, f[q]);
#pragma unroll
    for (int s = 32; s; s >>= 1) m = fmaxf(m, __shfl_xor(m, s));
    float sum = 0.f;
#pragma unroll
    for (int q = 0; q < 8; ++q) { f[q] = expf(f[q] - m); sum += f[q]; }
#pragma unroll
    for (int s = 32; s; s >>= 1) sum += __shfl_xor(sum, s);
    float sc = 0.04419417382415922f / sum;
#pragma unroll
    for (int q = 0; q < 8; ++q) v[q] = (__bf16)(f[q] * sc);
    *(bf16x8*)p = v;
}

// ---------------- done head ----------------
__global__ __launch_bounds__(256) void done_kernel(const float* __restrict__ h,
                                                   const float* __restrict__ w,
                                                   const float* __restrict__ b,
                                                   float* __restrict__ out) {
    int row = blockIdx.x * 4 + (threadIdx.x >> 6);
    int lane = threadIdx.x & 63;
    float4 hv = *(const float4*)(h + (long)row * 256 + lane * 4);
    float4 w0 = *(const float4*)(w + lane * 8);
    float4 w1 = *(const float4*)(w + lane * 8 + 4);
    float d0 = hv.x * w0.x + hv.y * w0.z + hv.z * w1.x + hv.w * w1.z;
    float d1 = hv.x * w0.y + hv.y * w0.w + hv.z * w1.y + hv.w * w1.w;
#pragma unroll
    for (int s = 32; s; s >>= 1) { d0 += __shfl_xor(d0, s); d1 += __shfl_xor(d1, s); }
    if (lane == 0) {
        out[(long)row * 2 + 0] = 1.f / (1.f + expf(-(d0 + b[0])));
        out[(long)row * 2 + 1] = 1.f / (1.f + expf(-(d1 + b[1])));
    }
}

// ---------------- launch ----------------
extern "C" void kernel_launch(void* const* d_in, const int* in_sizes, int n_in,
                              void* d_out, int out_size, void* d_ws, size_t ws_size,
                              hipStream_t stream) {
    const float* inputs  = (const float*)d_in[0];
    const float* keys    = (const float*)d_in[1];
    const float* values  = (const float*)d_in[2];
    const float* w_first = (const float*)d_in[3];
    const float* b_first = (const float*)d_in[4];
    const float* fc_w    = (const float*)d_in[5];
    const float* fc_b    = (const float*)d_in[6];
    const float* conv_w  = (const float*)d_in[7];
    const float* conv_b  = (const float*)d_in[8];
    const float* w1 = (const float*)d_in[9];  const float* b1 = (const float*)d_in[10];
    const float* w2 = (const float*)d_in[11]; const float* b2 = (const float*)d_in[12];
    const float* w3 = (const float*)d_in[13]; const float* b3 = (const float*)d_in[14];
    const float* wo = (const float*)d_in[15]; const float* bo = (const float*)d_in[16];
    const float* w_done = (const float*)d_in[17]; const float* b_done = (const float*)d_in[18];
    const float* w_mel  = (const float*)d_in[19]; const float* b_mel  = (const float*)d_in[20];
    float* out = (float*)d_out;
    float* ws  = (float*)d_ws;

    // ---- f32 region ----
    float* peq = ws;                 // 262144
    float* pek = peq + 262144;       // 131072
    float* zp  = pek + 131072;       // 64
    float* h   = zp + 64;            // 8388608
    // ---- bf16 region ----
    __bf16* bfb   = (__bf16*)(h + 8388608);
    __bf16* h_bf  = bfb;                   // 8388608
    __bf16* hq_bf = h_bf  + 8388608;       // 8388608
    __bf16* y_bf  = hq_bf + 8388608;       // 16777216
    __bf16* q_bf  = y_bf  + 16777216;      // 8388608
    __bf16* k_bf  = q_bf  + 8388608;       // 4194304
    __bf16* kpe_bf= k_bf  + 4194304;       // 4194304
    __bf16* val_bf= kpe_bf+ 4194304;       // 4194304
    __bf16* vT_bf = val_bf+ 4194304;       // 4194304
    __bf16* awb   = vT_bf + 4194304;       // 16777216 (also in_bf prologue scratch)
    __bf16* ctx_bf= awb   + 16777216;      // 8388608
    __bf16* wfT   = ctx_bf+ 8388608;       // 81920  [256][320]
    __bf16* fcT   = wfT   + 81920;         // 196608 [3][256][256]
    __bf16* convT = fcT   + 196608;        // 2621440 [4][512][1280]
    __bf16* w1T   = convT + 2621440;       // 262144
    __bf16* w2T   = w1T   + 262144;        // 262144
    __bf16* w3T   = w2T   + 262144;        // 262144
    __bf16* woT   = w3T   + 262144;        // 262144
    __bf16* wmT   = woT   + 262144;        // 81920  [320][256]
    __bf16* in_bf = awb;                   // alias: used only before layer 0

    dim3 blk(256);

    pos_enc_kernel<<<1024, 256, 0, stream>>>(peq, 1024, 1.0f);
    pos_enc_kernel<<<512, 256, 0, stream>>>(pek, 512, 2.0f);
    zero_init<<<1, 64, 0, stream>>>(zp);

    cvt_bf<<<5120, 256, 0, stream>>>(inputs, in_bf, 1310720);
    cvt_bf<<<2048, 256, 0, stream>>>(values, val_bf, 524288);
    kpe_kernel<<<2048, 256, 0, stream>>>(keys, pek, kpe_bf);

    transpose_k<<<dim3(8, 10, 1), blk, 0, stream>>>(w_first, wfT, 320, 256, 0, 0);
    transpose_k<<<dim3(8, 8, 3), blk, 0, stream>>>(fc_w, fcT, 256, 256, 65536, 65536);
    transpose_k<<<dim3(16, 40, 4), blk, 0, stream>>>(conv_w, convT, 1280, 512, 655360, 655360);
    transpose_k<<<dim3(8, 8, 4), blk, 0, stream>>>(w1, w1T, 256, 256, 65536, 65536);
    transpose_k<<<dim3(8, 8, 4), blk, 0, stream>>>(w2, w2T, 256, 256, 65536, 65536);
    transpose_k<<<dim3(8, 8, 4), blk, 0, stream>>>(w3, w3T, 256, 256, 65536, 65536);
    transpose_k<<<dim3(8, 8, 4), blk, 0, stream>>>(wo, woT, 256, 256, 65536, 65536);
    transpose_k<<<dim3(10, 8, 1), blk, 0, stream>>>(w_mel, wmT, 256, 320, 0, 0);

    // FC chain: in_bf -> h_bf -> hq_bf -> ctx_bf -> (h, h_bf)
    gemm_bf<1, 1, 1, 0><<<dim3(2, 256, 1), blk, 0, stream>>>(
        in_bf, wfT, b_first, nullptr, nullptr, h_bf, 32768, 256, 320, 0, 0, 0);
    gemm_bf<1, 1, 1, 0><<<dim3(2, 256, 1), blk, 0, stream>>>(
        h_bf, fcT + 0 * 65536, fc_b + 0 * 256, nullptr, nullptr, hq_bf, 32768, 256, 256, 0, 0, 0);
    gemm_bf<1, 1, 1, 0><<<dim3(2, 256, 1), blk, 0, stream>>>(
        hq_bf, fcT + 1 * 65536, fc_b + 1 * 256, nullptr, nullptr, ctx_bf, 32768, 256, 256, 0, 0, 0);
    gemm_bf<1, 1, 2, 0><<<dim3(2, 256, 1), blk, 0, stream>>>(
        ctx_bf, fcT + 2 * 65536, fc_b + 2 * 256, nullptr, h, h_bf, 32768, 256, 256, 0, 0, 0);

    for (int l = 0; l < 4; ++l) {
        int dil = 1 << l;
        conv_bf<<<dim3(4, 256, 1), blk, 0, stream>>>(
            h_bf, convT + (long)l * 655360, conv_b + l * 512, y_bf, dil, (const __bf16*)zp);
        glu_kernel<<<4096, 256, 0, stream>>>(h, y_bf, peq, h_bf, hq_bf);
        // q = (h+peq) @ w2 + b2 -> bf16
        gemm_bf<1, 0, 1, 0><<<dim3(2, 256, 1), blk, 0, stream>>>(
            hq_bf, w2T + (long)l * 65536, b2 + l * 256, nullptr, nullptr, q_bf, 32768, 256, 256, 0, 0, 0);
        // k = (keys+pek) @ w1 + b1 -> bf16
        gemm_bf<1, 0, 1, 0><<<dim3(2, 128, 1), blk, 0, stream>>>(
            kpe_bf, w1T + (long)l * 65536, b1 + l * 256, nullptr, nullptr, k_bf, 16384, 256, 256, 0, 0, 0);
        // vT_z = w3T @ values_z^T + b3(row) -> bf16 [256][512]
        gemm_bf<2, 0, 1, 0><<<dim3(4, 2, 32), blk, 0, stream>>>(
            w3T + (long)l * 65536, val_bf, b3 + l * 256, nullptr, nullptr, vT_bf,
            256, 512, 256, 0, 512 * 256, 256 * 512);
        // scores -> bf16
        gemm_bf<0, 0, 1, 0><<<dim3(4, 8, 32), blk, 0, stream>>>(
            q_bf, k_bf, nullptr, nullptr, nullptr, awb,
            1024, 512, 256, 1024 * 256, 512 * 256, 1024 * 512);
        softmax_bf<<<8192, 256, 0, stream>>>(awb);
        // ctx = al @ v -> bf16
        gemm_bf<0, 0, 1, 0><<<dim3(2, 8, 32), blk, 0, stream>>>(
            awb, vT_bf, nullptr, nullptr, nullptr, ctx_bf,
            1024, 256, 512, 1024 * 512, 256 * 512, 1024 * 256);
        // h = (ctx @ wo + bo + h) * SQH -> f32 + bf16
        gemm_bf<1, 0, 2, 1><<<dim3(2, 256, 1), blk, 0, stream>>>(
            ctx_bf, woT + (long)l * 65536, bo + l * 256, h, h, h_bf, 32768, 256, 256, 0, 0, 0);
    }

    gemm_bf<1, 0, 0, 0><<<dim3(3, 256, 1), blk, 0, stream>>>(
        h_bf, wmT, b_mel, nullptr, out, nullptr, 32768, 320, 256, 0, 0, 0);
    done_kernel<<<8192, 256, 0, stream>>>(h, w_done, b_done, out + 10485760);
    hipMemcpyAsync(out + 10551296, h, (size_t)8388608 * 4, hipMemcpyDeviceToDevice, stream);
}